// Round 6
// baseline (627.724 us; speedup 1.0000x reference)
//
#include <hip/hip_runtime.h>
#include <hip/hip_bf16.h>

typedef unsigned short u16;
typedef __attribute__((ext_vector_type(16))) float f32x16;
typedef __attribute__((ext_vector_type(8))) short bf16x8;

// ---------------------------------------------------------------------------
// helpers
// ---------------------------------------------------------------------------
__device__ __forceinline__ u16 f2bf(float f) {
    union { float f; unsigned u; } v; v.f = f;
    unsigned r = (v.u + 0x7fffu + ((v.u >> 16) & 1u)) >> 16;   // RNE
    return (u16)r;
}

__device__ __forceinline__ float softplus(float x) {
    return (x > 15.f) ? x : log1pf(__expf(x));
}

__device__ __forceinline__ void gload_lds16(const void* g, void* l) {
    __builtin_amdgcn_global_load_lds(
        (__attribute__((address_space(1))) void*)(g),
        (__attribute__((address_space(3))) void*)(l),
        16, 0, 0);
}

#define BAR() do { asm volatile("" ::: "memory"); \
                   __builtin_amdgcn_s_barrier();  \
                   asm volatile("" ::: "memory"); } while (0)

// chunk swizzle: must separate rows 8 AND 16 apart (32-row fragment span).
// sw(row) = (row&7) ^ (bit4(row)<<1); involution via XOR.
__device__ __forceinline__ int swz_row(int row) {
    return (row & 7) ^ (((row >> 4) & 1) << 1);
}

// ---------------------------------------------------------------------------
// prep kernels (BW-roofline already)
// ---------------------------------------------------------------------------
__global__ __launch_bounds__(256) void prep_x_kernel(
        const float* __restrict__ x, u16* __restrict__ xb, int n4) {
    int i = blockIdx.x * 256 + threadIdx.x;
    if (i >= n4) return;
    float4 v = ((const float4*)x)[i];
    ushort4 o;
    o.x = f2bf(v.x); o.y = f2bf(v.y); o.z = f2bf(v.z); o.w = f2bf(v.w);
    ((ushort4*)xb)[i] = o;
}

__global__ __launch_bounds__(256) void prep_w_kernel(
        const float* __restrict__ mu, const float* __restrict__ rho,
        const float* __restrict__ eps, u16* __restrict__ wb, int n4) {
    int i = blockIdx.x * 256 + threadIdx.x;
    if (i >= n4) return;
    float4 m = ((const float4*)mu)[i];
    float4 r = ((const float4*)rho)[i];
    float4 e = ((const float4*)eps)[i];
    ushort4 o;
    o.x = f2bf(m.x + softplus(r.x) * e.x);
    o.y = f2bf(m.y + softplus(r.y) * e.y);
    o.z = f2bf(m.z + softplus(r.z) * e.z);
    o.w = f2bf(m.w + softplus(r.w) * e.w);
    ((ushort4*)wb)[i] = o;
}

__global__ __launch_bounds__(256) void prep_bias_kernel(
        const float* __restrict__ mu, const float* __restrict__ rho,
        const float* __restrict__ eps, float* __restrict__ b, int n) {
    int i = blockIdx.x * 256 + threadIdx.x;
    if (i < n) b[i] = mu[i] + softplus(rho[i]) * eps[i];
}

// ---------------------------------------------------------------------------
// 256x256 8-phase bf16 GEMM (B^T) + bias — 32x32x16 MFMA, conflict-fixed
// swizzle. Per-wave output 128x64 = 4x2 tiles of 32x32; 8 MFMA/phase with
// 4 independent accumulators. LDS 128 KiB; physical chunk = logical ^ sw(row)
// with sw = (row&7)^(bit4(row)<<1) so co-serviced lanes {i,i+16,i+32,i+48}
// land on 4 distinct bank groups. Staging inverse-swizzles the global source.
// ---------------------------------------------------------------------------
__device__ __forceinline__ bf16x8 ld_frag32(const u16* region, int r0, int kc16, int lane) {
    int row = r0 + (lane & 31);
    int kc  = (kc16 * 2 + (lane >> 5)) ^ swz_row(row);
    return *(const bf16x8*)((const char*)region + row * 128 + kc * 16);
}

// one phase's MFMA cluster: 2 m-tiles x 2 n-tiles x 2 k-sub (s)
template <int MB>
__device__ __forceinline__ void mfma8(f32x16 (&acc)[4][2],
                                      const bf16x8 (&av)[2][2],
                                      const bf16x8 (&bv)[2][2]) {
#pragma unroll
    for (int s = 0; s < 2; ++s)
#pragma unroll
        for (int mi = 0; mi < 2; ++mi)
#pragma unroll
            for (int ni = 0; ni < 2; ++ni)
                acc[MB + mi][ni] = __builtin_amdgcn_mfma_f32_32x32x16_bf16(
                    av[mi][s], bv[ni][s], acc[MB + mi][ni], 0, 0, 0);
}

// stage one half-unit (128 rows x 64 k): 2 x global_load_lds(16B) per thread
#define STAGE(region, h, P, koff) do {                                          \
    gload_lds16(P[h][0] + (koff), (char*)(region) + (h) * 16384 + (w * 2 + 0) * 1024); \
    gload_lds16(P[h][1] + (koff), (char*)(region) + (h) * 16384 + (w * 2 + 1) * 1024); \
} while (0)

// read A frags for (m-half mh, k-half kh):  a[mi][s]
#define RD_A32(reg, mh, kh)                                            \
    _Pragma("unroll")                                                  \
    for (int mi = 0; mi < 2; ++mi)                                     \
        _Pragma("unroll")                                              \
        for (int s = 0; s < 2; ++s)                                    \
            a[mi][s] = ld_frag32(reg, wr * 128 + (mh) * 64 + mi * 32, (kh) * 2 + s, lane)

// read B frags for k-half kh into bb[kh]
#define RD_B32(reg, kh)                                                \
    _Pragma("unroll")                                                  \
    for (int ni = 0; ni < 2; ++ni)                                     \
        _Pragma("unroll")                                              \
        for (int s = 0; s < 2; ++s)                                    \
            bb[kh][ni][s] = ld_frag32(reg, wc * 64 + ni * 32, (kh) * 2 + s, lane)

__global__ __launch_bounds__(512, 2) void gemm256_8ph(
        const u16* __restrict__ A,   // [M][K] bf16
        const u16* __restrict__ B,   // [Nout][K] bf16
        const float* __restrict__ bias,
        float* __restrict__ C,       // [M][Nout] fp32
        int M, int Nout, int K) {
    __shared__ __attribute__((aligned(16))) u16 smem[4][16384];  // A0,B0,A1,B1
    u16* A0 = smem[0]; u16* B0 = smem[1];
    u16* A1 = smem[2]; u16* B1 = smem[3];

    const int tid  = threadIdx.x;
    const int lane = tid & 63;
    const int w    = tid >> 6;     // wave 0..7
    const int wr   = w >> 2;       // 0..1 -> 128-row slice
    const int wc   = w & 3;        // 0..3 -> 64-col slice

    // bijective XCD swizzle (nwg % 8 == 0 here)
    const int nbn = Nout >> 8;
    const int nwg = (M >> 8) * nbn;
    const int cpx = nwg >> 3;
    const int swz = ((int)blockIdx.x & 7) * cpx + ((int)blockIdx.x >> 3);
    const int m0 = (swz / nbn) << 8;
    const int n0 = (swz % nbn) << 8;

    // per-thread staging source pointers (inverse-swizzled global chunks)
    const u16* PA[2][2]; const u16* PB[2][2];
#pragma unroll
    for (int q = 0; q < 2; ++q) {
        int c   = (w * 2 + q) * 64 + lane;
        int row = c >> 3;                       // half-local row 0..127
        int kc  = (c & 7) ^ swz_row(row);       // logical chunk for this slot
#pragma unroll
        for (int h = 0; h < 2; ++h) {
            PA[h][q] = A + (size_t)(m0 + h * 128 + row) * K + kc * 8;
            PB[h][q] = B + (size_t)(n0 + h * 128 + row) * K + kc * 8;
        }
    }

    bf16x8 a[2][2], bb[2][2][2];   // a: cur (m-half,k-half); bb: both k-halves of B
    f32x16 acc[4][2] = {};         // 4 m-tiles x 2 n-tiles of 32x32

    const int NT = K >> 6;    // K-tiles
    const int NI = NT >> 1;   // iterations (2 tiles each)

    // prologue: tile0 full + B1(t1) full + A1-lo(t1); vmcnt(6) -> tile0 landed,
    // {B1-lo,B1-hi,A1-lo} flying (steady-state entry).
    STAGE(B0, 0, PB, 0);  STAGE(B0, 1, PB, 0);
    STAGE(A0, 0, PA, 0);  STAGE(A0, 1, PA, 0);
    STAGE(B1, 0, PB, 64); STAGE(B1, 1, PB, 64);
    STAGE(A1, 0, PA, 64);
    asm volatile("s_waitcnt vmcnt(6)" ::: "memory");
    BAR();

#pragma unroll 1
    for (int i = 0; i < NI; ++i) {
        int t2 = 2 * i + 2; if (t2 >= NT) t2 -= NT;
        int t3 = 2 * i + 3; if (t3 >= NT) t3 -= NT;
        const int k1 = (2 * i + 1) << 6;
        const int k2 = t2 << 6;
        const int k3 = t3 << 6;

        // ---- PH1: (m-lo, k-lo)  reads a(4)+bb0(4) | stage A1-hi(t1)
        RD_A32(A0, 0, 0);
        RD_B32(B0, 0);
        STAGE(A1, 1, PA, k1);
        BAR();
        asm volatile("s_waitcnt lgkmcnt(0)" ::: "memory");
        __builtin_amdgcn_s_setprio(1);
        mfma8<0>(acc, a, bb[0]);
        __builtin_amdgcn_s_setprio(0);
        BAR();

        // ---- PH2: (m-lo, k-hi)  reads a(4)+bb1(4)
        RD_A32(A0, 0, 1);
        RD_B32(B0, 1);
        BAR();
        asm volatile("s_waitcnt lgkmcnt(0)" ::: "memory");
        __builtin_amdgcn_s_setprio(1);
        mfma8<0>(acc, a, bb[1]);
        __builtin_amdgcn_s_setprio(0);
        BAR();

        // ---- PH3: (m-hi, k-lo)  reads a(4), bb0 held | stage B0-lo(t2)
        RD_A32(A0, 1, 0);
        STAGE(B0, 0, PB, k2);
        BAR();
        asm volatile("s_waitcnt lgkmcnt(0)" ::: "memory");
        __builtin_amdgcn_s_setprio(1);
        mfma8<2>(acc, a, bb[0]);
        __builtin_amdgcn_s_setprio(0);
        BAR();

        // ---- PH4: (m-hi, k-hi)  reads a(4), bb1 held | stage B0-hi(t2);
        //      vmcnt(4): t1 (incl A1-hi) landed; A0-lo(t2) staged post-MFMA
        RD_A32(A0, 1, 1);
        STAGE(B0, 1, PB, k2);
        asm volatile("s_waitcnt vmcnt(4)" ::: "memory");
        BAR();
        asm volatile("s_waitcnt lgkmcnt(0)" ::: "memory");
        __builtin_amdgcn_s_setprio(1);
        mfma8<2>(acc, a, bb[1]);
        __builtin_amdgcn_s_setprio(0);
        STAGE(A0, 0, PA, k2);
        BAR();

        // ---- PH5: buf1 (m-lo, k-lo) | stage A0-hi(t2)
        RD_A32(A1, 0, 0);
        RD_B32(B1, 0);
        STAGE(A0, 1, PA, k2);
        BAR();
        asm volatile("s_waitcnt lgkmcnt(0)" ::: "memory");
        __builtin_amdgcn_s_setprio(1);
        mfma8<0>(acc, a, bb[0]);
        __builtin_amdgcn_s_setprio(0);
        BAR();

        // ---- PH6: buf1 (m-lo, k-hi)
        RD_A32(A1, 0, 1);
        RD_B32(B1, 1);
        BAR();
        asm volatile("s_waitcnt lgkmcnt(0)" ::: "memory");
        __builtin_amdgcn_s_setprio(1);
        mfma8<0>(acc, a, bb[1]);
        __builtin_amdgcn_s_setprio(0);
        BAR();

        // ---- PH7: buf1 (m-hi, k-lo) | stage B1-lo(t3)
        RD_A32(A1, 1, 0);
        STAGE(B1, 0, PB, k3);
        BAR();
        asm volatile("s_waitcnt lgkmcnt(0)" ::: "memory");
        __builtin_amdgcn_s_setprio(1);
        mfma8<2>(acc, a, bb[0]);
        __builtin_amdgcn_s_setprio(0);
        BAR();

        // ---- PH8: buf1 (m-hi, k-hi) | stage B1-hi(t3); vmcnt(4): t2 landed;
        //      A1-lo(t3) staged post-MFMA
        RD_A32(A1, 1, 1);
        STAGE(B1, 1, PB, k3);
        asm volatile("s_waitcnt vmcnt(4)" ::: "memory");
        BAR();
        asm volatile("s_waitcnt lgkmcnt(0)" ::: "memory");
        __builtin_amdgcn_s_setprio(1);
        mfma8<2>(acc, a, bb[1]);
        __builtin_amdgcn_s_setprio(0);
        STAGE(A1, 0, PA, k3);
        BAR();
    }

    asm volatile("s_waitcnt vmcnt(0)" ::: "memory");  // drain wrapped prefetch

    // epilogue: 32x32 C/D layout  col = lane&31, row = (reg&3)+8*(reg>>2)+4*(lane>>5)
    const int ccol = lane & 31;
    const int crow = 4 * (lane >> 5);
#pragma unroll
    for (int mi = 0; mi < 4; ++mi) {
#pragma unroll
        for (int ni = 0; ni < 2; ++ni) {
            const int col = n0 + wc * 64 + ni * 32 + ccol;
            const float bv = bias[col];
            const int rbase = m0 + wr * 128 + mi * 32 + crow;
            float* Cp = C + (size_t)rbase * Nout + col;
#pragma unroll
            for (int reg = 0; reg < 16; ++reg) {
                const int roff = (reg & 3) + 8 * (reg >> 2);
                Cp[(size_t)roff * Nout] = acc[mi][ni][reg] + bv;
            }
        }
    }
}

// ---------------------------------------------------------------------------
// launch
// ---------------------------------------------------------------------------
extern "C" void kernel_launch(void* const* d_in, const int* in_sizes, int n_in,
                              void* d_out, int out_size, void* d_ws, size_t ws_size,
                              hipStream_t stream) {
    const float* x    = (const float*)d_in[0];
    const float* wmu  = (const float*)d_in[1];
    const float* wrho = (const float*)d_in[2];
    const float* bmu  = (const float*)d_in[3];
    const float* brho = (const float*)d_in[4];
    const float* ew   = (const float*)d_in[5];
    const float* eb   = (const float*)d_in[6];
    float* out = (float*)d_out;

    const int Nout = in_sizes[3];            // 4096
    const int K    = in_sizes[1] / Nout;     // 4096
    const int M    = in_sizes[0] / K;        // 16384

    u16* xb = (u16*)d_ws;
    u16* wb = xb + (size_t)M * K;
    float* bs = (float*)(wb + (size_t)Nout * K);

    const int nx4 = (M * K) / 4;
    const int nw4 = (Nout * K) / 4;
    prep_x_kernel<<<(nx4 + 255) / 256, 256, 0, stream>>>(x, xb, nx4);
    prep_w_kernel<<<(nw4 + 255) / 256, 256, 0, stream>>>(wmu, wrho, ew, wb, nw4);
    prep_bias_kernel<<<(Nout + 255) / 256, 256, 0, stream>>>(bmu, brho, eb, bs, Nout);

    dim3 grid((M / 256) * (Nout / 256));
    gemm256_8ph<<<grid, 512, 0, stream>>>(xb, wb, bs, out, M, Nout, K);
}

// Round 7
// 566.095 us; speedup vs baseline: 1.1089x; 1.1089x over previous
//
#include <hip/hip_runtime.h>
#include <hip/hip_bf16.h>

typedef unsigned short u16;
typedef __attribute__((ext_vector_type(4))) float f32x4;
typedef __attribute__((ext_vector_type(8))) short bf16x8;

// ---------------------------------------------------------------------------
// helpers
// ---------------------------------------------------------------------------
__device__ __forceinline__ u16 f2bf(float f) {
    union { float f; unsigned u; } v; v.f = f;
    unsigned r = (v.u + 0x7fffu + ((v.u >> 16) & 1u)) >> 16;   // RNE
    return (u16)r;
}

__device__ __forceinline__ float softplus(float x) {
    return (x > 15.f) ? x : log1pf(__expf(x));
}

__device__ __forceinline__ void gload_lds16(const void* g, void* l) {
    __builtin_amdgcn_global_load_lds(
        (__attribute__((address_space(1))) void*)(g),
        (__attribute__((address_space(3))) void*)(l),
        16, 0, 0);
}

#define BAR() do { asm volatile("" ::: "memory"); \
                   __builtin_amdgcn_s_barrier();  \
                   asm volatile("" ::: "memory"); } while (0)

// ---------------------------------------------------------------------------
// fused prep: x->bf16, W = mu + softplus(rho)*eps -> bf16, bias (f32)
// ---------------------------------------------------------------------------
__global__ __launch_bounds__(256) void prep_all(
        const float* __restrict__ x,
        const float* __restrict__ wmu, const float* __restrict__ wrho,
        const float* __restrict__ ew,
        const float* __restrict__ bmu, const float* __restrict__ brho,
        const float* __restrict__ eb,
        u16* __restrict__ xb, u16* __restrict__ wb, float* __restrict__ bs,
        int nx4, int nw4, int nb) {
    int i = blockIdx.x * 256 + threadIdx.x;
    if (i < nx4) {
        float4 v = ((const float4*)x)[i];
        ushort4 o;
        o.x = f2bf(v.x); o.y = f2bf(v.y); o.z = f2bf(v.z); o.w = f2bf(v.w);
        ((ushort4*)xb)[i] = o;
    }
    if (i < nw4) {
        float4 m = ((const float4*)wmu)[i];
        float4 r = ((const float4*)wrho)[i];
        float4 e = ((const float4*)ew)[i];
        ushort4 o;
        o.x = f2bf(m.x + softplus(r.x) * e.x);
        o.y = f2bf(m.y + softplus(r.y) * e.y);
        o.z = f2bf(m.z + softplus(r.z) * e.z);
        o.w = f2bf(m.w + softplus(r.w) * e.w);
        ((ushort4*)wb)[i] = o;
    }
    if (i < nb) {
        bs[i] = bmu[i] + softplus(brho[i]) * eb[i];
    }
}

// ---------------------------------------------------------------------------
// 256x256 8-phase bf16 GEMM (B^T) + bias — round-3 loop (best measured:
// 477 us, 0 bank conflicts) + LDS-staged float4 epilogue.
// LDS: 2 dbuf x {A,B} x [256][64] bf16, chunk-XOR swizzle kc ^= row&7;
// reads 4/4/8/8 per phase; vmcnt(4) at PH4/PH8.
// ---------------------------------------------------------------------------
__device__ __forceinline__ bf16x8 ld_frag(const u16* region, int r0, int ks, int lane) {
    int row = r0 + (lane & 15);
    int kc  = (ks * 4 + (lane >> 4)) ^ (row & 7);
    return *(const bf16x8*)((const char*)region + row * 128 + kc * 16);
}

template <int MB, int NB>
__device__ __forceinline__ void mfma_quad(f32x4 (&acc)[8][4],
                                          const bf16x8 (&av)[4][2],
                                          const bf16x8 (&bv)[2][2]) {
#pragma unroll
    for (int ks = 0; ks < 2; ++ks)
#pragma unroll
        for (int mi = 0; mi < 4; ++mi)
#pragma unroll
            for (int ni = 0; ni < 2; ++ni)
                acc[MB + mi][NB + ni] = __builtin_amdgcn_mfma_f32_16x16x32_bf16(
                    av[mi][ks], bv[ni][ks], acc[MB + mi][NB + ni], 0, 0, 0);
}

#define STAGE(region, h, P, koff) do {                                          \
    gload_lds16(P[h][0] + (koff), (char*)(region) + (h) * 16384 + (w * 2 + 0) * 1024); \
    gload_lds16(P[h][1] + (koff), (char*)(region) + (h) * 16384 + (w * 2 + 1) * 1024); \
} while (0)

#define RD_A(reg, roff)                                                \
    _Pragma("unroll")                                                  \
    for (int mi = 0; mi < 4; ++mi)                                     \
        _Pragma("unroll")                                              \
        for (int ks = 0; ks < 2; ++ks)                                 \
            a[mi][ks] = ld_frag(reg, wr * 128 + (roff) + mi * 16, ks, lane)

#define RD_B(dst, reg, roff)                                           \
    _Pragma("unroll")                                                  \
    for (int ni = 0; ni < 2; ++ni)                                     \
        _Pragma("unroll")                                              \
        for (int ks = 0; ks < 2; ++ks)                                 \
            dst[ni][ks] = ld_frag(reg, wc * 64 + (roff) + ni * 16, ks, lane)

__global__ __launch_bounds__(512, 2) void gemm256_8ph(
        const u16* __restrict__ A,   // [M][K] bf16
        const u16* __restrict__ B,   // [Nout][K] bf16
        const float* __restrict__ bias,
        float* __restrict__ C,       // [M][Nout] fp32
        int M, int Nout, int K) {
    __shared__ __attribute__((aligned(16))) u16 smem[4][16384];  // A0,B0,A1,B1
    u16* A0 = smem[0]; u16* B0 = smem[1];
    u16* A1 = smem[2]; u16* B1 = smem[3];

    const int tid  = threadIdx.x;
    const int lane = tid & 63;
    const int w    = tid >> 6;     // wave 0..7
    const int wr   = w >> 2;       // 0..1 -> 128-row slice
    const int wc   = w & 3;        // 0..3 -> 64-col slice

    // bijective XCD swizzle (nwg % 8 == 0 here)
    const int nbn = Nout >> 8;
    const int nwg = (M >> 8) * nbn;
    const int cpx = nwg >> 3;
    const int swz = ((int)blockIdx.x & 7) * cpx + ((int)blockIdx.x >> 3);
    const int m0 = (swz / nbn) << 8;
    const int n0 = (swz % nbn) << 8;

    // per-thread staging source pointers (inverse-swizzled global chunks)
    const u16* PA[2][2]; const u16* PB[2][2];
#pragma unroll
    for (int q = 0; q < 2; ++q) {
        int c   = (w * 2 + q) * 64 + lane;
        int row = c >> 3;
        int kc  = (c & 7) ^ (row & 7);
#pragma unroll
        for (int h = 0; h < 2; ++h) {
            PA[h][q] = A + (size_t)(m0 + h * 128 + row) * K + kc * 8;
            PB[h][q] = B + (size_t)(n0 + h * 128 + row) * K + kc * 8;
        }
    }

    bf16x8 a[4][2], bl[2][2], bh[2][2];
    f32x4 acc[8][4] = {};

    const int NT = K >> 6;    // K-tiles
    const int NI = NT >> 1;   // iterations (2 tiles each)

    // prologue: tile0 -> buf0 (all), tile1 -> buf1 (B units)
    STAGE(B0, 0, PB, 0);  STAGE(B0, 1, PB, 0);
    STAGE(A0, 0, PA, 0);  STAGE(A0, 1, PA, 0);
    STAGE(B1, 0, PB, 64); STAGE(B1, 1, PB, 64);
    asm volatile("s_waitcnt vmcnt(4)" ::: "memory");   // tile0 landed
    BAR();
    RD_A(A0, 0);   // al pre-read for PH1 (matches PH8-exit state)

#pragma unroll 1
    for (int i = 0; i < NI; ++i) {
        int t2 = 2 * i + 2; if (t2 >= NT) t2 -= NT;
        int t3 = 2 * i + 3; if (t3 >= NT) t3 -= NT;
        const int k1 = (2 * i + 1) << 6;
        const int k2 = t2 << 6;
        const int k3 = t3 << 6;

        // -------- PH1: q0 = al x bl          | reads bl(4) | stage A1-lo(t1)
        RD_B(bl, B0, 0);
        STAGE(A1, 0, PA, k1);
        BAR();
        asm volatile("s_waitcnt lgkmcnt(0)" ::: "memory");
        __builtin_amdgcn_s_setprio(1);
        mfma_quad<0, 0>(acc, a, bl);
        __builtin_amdgcn_s_setprio(0);
        BAR();

        // -------- PH2: q1 = al x bh          | reads bh(4) | stage A1-hi(t1)
        RD_B(bh, B0, 32);
        STAGE(A1, 1, PA, k1);
        BAR();
        asm volatile("s_waitcnt lgkmcnt(0)" ::: "memory");
        __builtin_amdgcn_s_setprio(1);
        mfma_quad<0, 2>(acc, a, bh);
        __builtin_amdgcn_s_setprio(0);
        BAR();

        // -------- PH3: q2 = ah x bh          | reads ah(8) | stage B0-lo(t2)
        RD_A(A0, 64);
        STAGE(B0, 0, PB, k2);
        BAR();
        asm volatile("s_waitcnt lgkmcnt(0)" ::: "memory");
        __builtin_amdgcn_s_setprio(1);
        mfma_quad<4, 2>(acc, a, bh);
        __builtin_amdgcn_s_setprio(0);
        BAR();

        // -------- PH4: q3 = ah x bl | stage B0-hi(t2) | vmcnt(4): t1 landed
        //          then read al'(8) from A1 (hidden under q3's MFMA drain)
        STAGE(B0, 1, PB, k2);
        asm volatile("s_waitcnt vmcnt(4)" ::: "memory");
        BAR();
        __builtin_amdgcn_s_setprio(1);
        mfma_quad<4, 0>(acc, a, bl);
        __builtin_amdgcn_s_setprio(0);
        RD_A(A1, 0);
        BAR();

        // -------- PH5: q0' = al' x bl'       | reads bl'(4) | stage A0-lo(t2)
        RD_B(bl, B1, 0);
        STAGE(A0, 0, PA, k2);
        BAR();
        asm volatile("s_waitcnt lgkmcnt(0)" ::: "memory");
        __builtin_amdgcn_s_setprio(1);
        mfma_quad<0, 0>(acc, a, bl);
        __builtin_amdgcn_s_setprio(0);
        BAR();

        // -------- PH6: q1' = al' x bh'       | reads bh'(4) | stage A0-hi(t2)
        RD_B(bh, B1, 32);
        STAGE(A0, 1, PA, k2);
        BAR();
        asm volatile("s_waitcnt lgkmcnt(0)" ::: "memory");
        __builtin_amdgcn_s_setprio(1);
        mfma_quad<0, 2>(acc, a, bh);
        __builtin_amdgcn_s_setprio(0);
        BAR();

        // -------- PH7: q2' = ah' x bh'       | reads ah'(8) | stage B1-lo(t3)
        RD_A(A1, 64);
        STAGE(B1, 0, PB, k3);
        BAR();
        asm volatile("s_waitcnt lgkmcnt(0)" ::: "memory");
        __builtin_amdgcn_s_setprio(1);
        mfma_quad<4, 2>(acc, a, bh);
        __builtin_amdgcn_s_setprio(0);
        BAR();

        // -------- PH8: q3' = ah' x bl' | stage B1-hi(t3) | vmcnt(4): t2 landed
        //          then read al''(8) from A0 for next iteration's PH1
        STAGE(B1, 1, PB, k3);
        asm volatile("s_waitcnt vmcnt(4)" ::: "memory");
        BAR();
        __builtin_amdgcn_s_setprio(1);
        mfma_quad<4, 0>(acc, a, bl);
        __builtin_amdgcn_s_setprio(0);
        RD_A(A0, 0);
        BAR();
    }

    // ---- epilogue: all waves must drain DMA before LDS reuse (a peer wave's
    // in-flight gload_lds writes into every wave's epilogue region).
    asm volatile("s_waitcnt vmcnt(0)" ::: "memory");
    BAR();

    // wave-private 16 KiB staging region; [64][64] f32 with col-XOR swizzle
    // cp = col ^ (((row>>2)&3)<<2). For the write side this equals crow.
    float* elds = (float*)((char*)smem + w * 16384);
    const int ccol = lane & 15;
    const int crow = (lane >> 4) * 4;

    float bv[4];
#pragma unroll
    for (int ni = 0; ni < 4; ++ni)
        bv[ni] = bias[n0 + wc * 64 + ni * 16 + ccol];

#pragma unroll
    for (int h = 0; h < 2; ++h) {
        // scatter 64x64 f32 (rows h*64..h*64+63 of wave tile) into LDS
#pragma unroll
        for (int mi = 0; mi < 4; ++mi)
#pragma unroll
            for (int ni = 0; ni < 4; ++ni)
#pragma unroll
                for (int q = 0; q < 4; ++q) {
                    int row_l = mi * 16 + crow + q;
                    int cp = (ni * 16 + ccol) ^ crow;
                    elds[row_l * 64 + cp] = acc[h * 4 + mi][ni][q] + bv[ni];
                }
        asm volatile("s_waitcnt lgkmcnt(0)" ::: "memory");
        // coalesced read-back + float4 stores (256B-dense per quarter-wave)
#pragma unroll
        for (int p = 0; p < 16; ++p) {
            int row_l = p * 4 + (lane >> 4);
            int cb = (lane & 15) * 4;
            float4 v = *(const float4*)&elds[row_l * 64 + (cb ^ ((p & 3) << 2))];
            float* Cp = C + (size_t)(m0 + wr * 128 + h * 64 + row_l) * Nout
                          + (n0 + wc * 64 + cb);
            *(float4*)Cp = v;
        }
        asm volatile("s_waitcnt lgkmcnt(0)" ::: "memory");  // WAR before h=1
    }
}

// ---------------------------------------------------------------------------
// launch
// ---------------------------------------------------------------------------
extern "C" void kernel_launch(void* const* d_in, const int* in_sizes, int n_in,
                              void* d_out, int out_size, void* d_ws, size_t ws_size,
                              hipStream_t stream) {
    const float* x    = (const float*)d_in[0];
    const float* wmu  = (const float*)d_in[1];
    const float* wrho = (const float*)d_in[2];
    const float* bmu  = (const float*)d_in[3];
    const float* brho = (const float*)d_in[4];
    const float* ew   = (const float*)d_in[5];
    const float* eb   = (const float*)d_in[6];
    float* out = (float*)d_out;

    const int Nout = in_sizes[3];            // 4096
    const int K    = in_sizes[1] / Nout;     // 4096
    const int M    = in_sizes[0] / K;        // 16384

    u16* xb = (u16*)d_ws;
    u16* wb = xb + (size_t)M * K;
    float* bs = (float*)(wb + (size_t)Nout * K);

    const int nx4 = (M * K) / 4;
    const int nw4 = (Nout * K) / 4;
    prep_all<<<(nx4 + 255) / 256, 256, 0, stream>>>(
        x, wmu, wrho, ew, bmu, brho, eb, xb, wb, bs, nx4, nw4, Nout);

    dim3 grid((M / 256) * (Nout / 256));
    gemm256_8ph<<<grid, 512, 0, stream>>>(xb, wb, bs, out, M, Nout, K);
}